// Round 4
// baseline (1248.408 us; speedup 1.0000x reference)
//
#include <hip/hip_runtime.h>
#include <hip/hip_bf16.h>
#include <math.h>

#define BB 16
#define TT 512
#define NN 128
#define PREDN 256
#define DMC 32
#define LL 768
constexpr float EPSF = 1e-5f;

// ---------------- K0: per-(b,n) mean / std over T ----------------
__global__ void k_stats(const float* __restrict__ bx, float* __restrict__ mean,
                        float* __restrict__ stdev, float* __restrict__ rstd){
  int b = blockIdx.x, n = threadIdx.x;
  float s = 0.f, s2 = 0.f;
  const float* p = bx + (size_t)b*TT*NN + n;
  for(int t=0;t<TT;t++){ float v = p[(size_t)t*NN]; s += v; s2 += v*v; }
  float mu = s*(1.f/TT);
  float var = fmaxf(s2*(1.f/TT) - mu*mu, 0.f);
  float sd = sqrtf(var + EPSF);
  int i = b*NN + n;
  mean[i] = mu; stdev[i] = sd; rstd[i] = 1.f/sd;
}

// ---------------- K0b: xn[b,t,n] = (bx - mean)*rstd ----------------
__global__ void k_xn(const float* __restrict__ bx, const float* __restrict__ mean,
                     const float* __restrict__ rstd, float* __restrict__ xn){
  int t = blockIdx.x, b = blockIdx.y, n = threadIdx.x;
  size_t i = ((size_t)b*TT + t)*NN + n;
  int r = b*NN + n;
  xn[i] = (bx[i] - mean[r])*rstd[r];
}

// ---------------- K1: naive GEMM1  x[b,n,l] = sum_t xn[b,t,n]*le_w[l,t] + le_b[l]
__global__ __launch_bounds__(256) void k_gemm1(const float* __restrict__ xn, const float* __restrict__ lew,
    const float* __restrict__ leb, float* __restrict__ x){
  __shared__ float xr[TT];
  int row = blockIdx.x;           // 0..2047
  int b = row >> 7, n = row & 127;
  int tid = threadIdx.x;
  for(int t=tid;t<TT;t+=256) xr[t] = xn[((size_t)b*TT + t)*NN + n];
  __syncthreads();
  float acc0 = 0.f, acc1 = 0.f, acc2 = 0.f;
  int l0 = tid, l1 = tid + 256, l2 = tid + 512;
  const float* w0 = lew + (size_t)l0*TT;
  const float* w1 = lew + (size_t)l1*TT;
  const float* w2 = lew + (size_t)l2*TT;
  for(int t=0;t<TT;t++){
    float v = xr[t];
    acc0 = fmaf(v, w0[t], acc0);
    acc1 = fmaf(v, w1[t], acc1);
    acc2 = fmaf(v, w2[t], acc2);
  }
  size_t ro = (size_t)row*LL;
  x[ro + l0] = acc0 + leb[l0];
  x[ro + l1] = acc1 + leb[l1];
  x[ro + l2] = acc2 + leb[l2];
}

// ---------------- K2: a[:,0,l,n] = x[b,n,l] ----------------
__global__ void k_a0(const float* __restrict__ x, float* __restrict__ a){
  int l = blockIdx.x, b = blockIdx.y, n = threadIdx.x;
  a[(((size_t)b*3 + 0)*LL + l)*NN + n] = x[((size_t)b*NN + n)*LL + l];
}

// ---------------- K3: conv1d stride 12, kernel 12 ----------------
__global__ __launch_bounds__(128) void k_conv1(const float* __restrict__ x, const float* __restrict__ w,
                                               const float* __restrict__ bias, float* __restrict__ t1){
  __shared__ float xs[NN*12];
  int j = blockIdx.x, b = blockIdx.y, o = threadIdx.x;
  for(int i=o;i<NN*12;i+=NN){
    int ci = i/12, k = i%12;
    xs[i] = x[((size_t)b*NN + ci)*LL + j*12 + k];
  }
  __syncthreads();
  float acc = bias[o];
  const float* wp = w + (size_t)o*NN*12;
  #pragma unroll 8
  for(int i=0;i<NN*12;i++) acc = fmaf(xs[i], wp[i], acc);
  t1[((size_t)b*NN + o)*64 + j] = acc;
}

// ---------------- K4: BN stats per channel ----------------
__global__ void k_bnstats(const float* __restrict__ t, const float* __restrict__ g, const float* __restrict__ bb,
                          int Bcnt, int Jcnt, float* __restrict__ scale, float* __restrict__ shift){
  int o = blockIdx.x;
  int tot = Bcnt*Jcnt;
  float s = 0.f, s2 = 0.f;
  for(int i=threadIdx.x; i<tot; i+=blockDim.x){
    int b = i / Jcnt, j = i % Jcnt;
    float v = t[((size_t)b*NN + o)*Jcnt + j];
    s += v; s2 += v*v;
  }
  __shared__ float rs[256], rs2[256];
  rs[threadIdx.x] = s; rs2[threadIdx.x] = s2;
  __syncthreads();
  for(int st=128; st>0; st>>=1){
    if(threadIdx.x < st){ rs[threadIdx.x] += rs[threadIdx.x+st]; rs2[threadIdx.x] += rs2[threadIdx.x+st]; }
    __syncthreads();
  }
  if(threadIdx.x == 0){
    float mu = rs[0]/tot;
    float var = fmaxf(rs2[0]/tot - mu*mu, 0.f);
    float sc = g[o] * rsqrtf(var + EPSF);
    scale[o] = sc; shift[o] = bb[o] - mu*sc;
  }
}

// ---------------- K5: BN apply + ELU + transpose to (B, J, C) ----------------
__global__ void k_bnelu_t(const float* __restrict__ t, const float* __restrict__ scale,
                          const float* __restrict__ shift, int Jcnt, float* __restrict__ tt){
  int j = blockIdx.x, b = blockIdx.y, o = threadIdx.x;
  float v = t[((size_t)b*NN + o)*Jcnt + j]*scale[o] + shift[o];
  v = v > 0.f ? v : (expf(v) - 1.f);
  tt[((size_t)b*Jcnt + j)*NN + o] = v;
}

// ---------------- K6: spline tridiagonal solve (Thomas) ----------------
template<int LK>
__global__ void k_spline_solve(const float* __restrict__ y, float* __restrict__ M){
  constexpr int m = LK-2;
  const float Kc = 6.f*(LK-1)*(LK-1);
  __shared__ float cp[m];
  __shared__ float dp[m][NN];
  int b = blockIdx.x, c = threadIdx.x;
  if(c == 0){
    float cv = 0.25f; cp[0] = cv;
    for(int i=1;i<m;i++){ cv = 1.f/(4.f - cv); cp[i] = cv; }
  }
  __syncthreads();
  const float* yb = y + (size_t)b*LK*NN + c;
  float y0 = yb[0], y1 = yb[NN];
  float dprev = 0.f;
  for(int i=0;i<m;i++){
    float y2 = yb[(size_t)(i+2)*NN];
    float r = (y2 - 2.f*y1 + y0)*Kc;
    float d = (i == 0) ? r*0.25f : (r - dprev)*cp[i];
    dp[i][c] = d; dprev = d;
    y0 = y1; y1 = y2;
  }
  float* Mb = M + (size_t)b*LK*NN + c;
  float xv = dp[m-1][c];
  Mb[(size_t)m*NN] = xv;
  for(int i=m-2;i>=0;i--){
    xv = dp[i][c] - cp[i]*xv;
    Mb[(size_t)(i+1)*NN] = xv;
  }
  Mb[0] = 0.f;
  Mb[(size_t)(LK-1)*NN] = 0.f;
}

// ---------------- K7: spline evaluation -> a[:,ch,l,n] ----------------
template<int LK>
__global__ void k_spline_eval(const float* __restrict__ y, const float* __restrict__ M,
                              float* __restrict__ a, int ch){
  int l = blockIdx.x, b = blockIdx.y, c = threadIdx.x;
  constexpr float hh = 1.f/(LK-1);
  float q = (float)l * (1.f/(LL-1));
  int idx = (int)floorf(q*(LK-1));
  if(idx > LK-2) idx = LK-2;
  float s = q - idx*hh;
  float u = hh - s;
  const float* yb = y + ((size_t)b*LK + idx)*NN + c;
  const float* Mb = M + ((size_t)b*LK + idx)*NN + c;
  float yi = yb[0], yi1 = yb[NN], M0 = Mb[0], M1 = Mb[NN];
  constexpr float hh6 = hh*hh/6.f;
  float val = (M0*u*u*u + M1*s*s*s)*(1.f/(6.f*hh))
            + (yi  - M0*hh6)*(u*(1.f/hh))
            + (yi1 - M1*hh6)*(s*(1.f/hh));
  a[(((size_t)b*3 + ch)*LL + l)*NN + c] = val;
}

// ---------------- K8: conv1d stride 4, kernel 4 (input transposed layout) ----------------
__global__ __launch_bounds__(128) void k_conv2(const float* __restrict__ tt, const float* __restrict__ w,
                                               const float* __restrict__ bias, float* __restrict__ t2){
  __shared__ float ts[4*NN];
  int j = blockIdx.x, b = blockIdx.y, o = threadIdx.x;
  for(int i=o;i<4*NN;i+=NN) ts[i] = tt[((size_t)b*64 + j*4)*NN + i];
  __syncthreads();
  float acc = bias[o];
  const float* wp = w + (size_t)o*NN*4;
  #pragma unroll 4
  for(int ci=0;ci<NN;ci++){
    acc = fmaf(ts[0*NN+ci], wp[ci*4+0], acc);
    acc = fmaf(ts[1*NN+ci], wp[ci*4+1], acc);
    acc = fmaf(ts[2*NN+ci], wp[ci*4+2], acc);
    acc = fmaf(ts[3*NN+ci], wp[ci*4+3], acc);
  }
  t2[((size_t)b*NN + o)*16 + j] = acc;
}

// ---------------- K13: fused conv2d stage (a -> h1(LDS) -> h2), GELU exact ----------------
__global__ __launch_bounds__(256) void k_fusedconv(const float* __restrict__ a,
    const float* __restrict__ w0, const float* __restrict__ b0,
    const float* __restrict__ w1, const float* __restrict__ b1,
    const float* __restrict__ v0, const float* __restrict__ vb0,
    const float* __restrict__ v1, const float* __restrict__ vb1,
    float* __restrict__ h2){
  constexpr int TL = 8, TN = 32;
  __shared__ float as[3][TL+4][TN+4];        // 3 x 12 x 36
  __shared__ float h1s[DMC][TL+2][TN+2];     // 32 x 10 x 34
  __shared__ float w0s[DMC*3], w1s[DMC*27], b0s[DMC], b1s[DMC], v0s[DMC], v1s[DMC*9];
  __shared__ float vb;
  int tid = threadIdx.x;
  for(int i=tid;i<DMC*3;i+=256) w0s[i] = w0[i];
  for(int i=tid;i<DMC*27;i+=256) w1s[i] = w1[i];
  for(int i=tid;i<DMC*9;i+=256) v1s[i] = v1[i];
  if(tid < DMC){ b0s[tid] = b0[tid]; b1s[tid] = b1[tid]; v0s[tid] = v0[tid]; }
  if(tid == 0) vb = vb0[0] + vb1[0];
  int l0 = blockIdx.x*TL, n0 = blockIdx.y*TN, b = blockIdx.z;
  const float* ab = a + (size_t)b*3*LL*NN;
  float* asf = &as[0][0][0];
  for(int i=tid;i<3*(TL+4)*(TN+4);i+=256){
    int ch = i/((TL+4)*(TN+4));
    int rem = i%((TL+4)*(TN+4));
    int yy = rem/(TN+4), xx = rem%(TN+4);
    int gl = l0 + yy - 2, gn = n0 + xx - 2;
    float v = 0.f;
    if(gl >= 0 && gl < LL && gn >= 0 && gn < NN) v = ab[((size_t)ch*LL + gl)*NN + gn];
    asf[i] = v;
  }
  __syncthreads();
  float* h1f = &h1s[0][0][0];
  for(int idx=tid; idx<DMC*(TL+2)*(TN+2); idx+=256){
    int c = idx/((TL+2)*(TN+2));
    int rem = idx%((TL+2)*(TN+2));
    int yy = rem/(TN+2), xx = rem%(TN+2);
    int gl = l0 + yy - 1, gn = n0 + xx - 1;
    float val = 0.f;
    if(gl >= 0 && gl < LL && gn >= 0 && gn < NN){
      float s0 = 0.f;
      #pragma unroll
      for(int ci=0;ci<3;ci++) s0 = fmaf(w0s[c*3+ci], as[ci][yy+1][xx+1], s0);
      float s1 = 0.f;
      #pragma unroll
      for(int ci=0;ci<3;ci++)
        #pragma unroll
        for(int dy=0;dy<3;dy++)
          #pragma unroll
          for(int dx=0;dx<3;dx++)
            s1 = fmaf(w1s[((c*3+ci)*3+dy)*3+dx], as[ci][yy+dy][xx+dx], s1);
      float hv = 0.5f*(s0 + b0s[c] + s1 + b1s[c]);
      val = hv*0.5f*(1.f + erff(hv*0.70710678118654752f));
    }
    h1f[idx] = val;
  }
  __syncthreads();
  int yy = tid >> 5, xx = tid & 31;
  float s0 = 0.f, s1 = 0.f;
  #pragma unroll
  for(int c=0;c<DMC;c++){
    s0 = fmaf(v0s[c], h1s[c][yy+1][xx+1], s0);
    #pragma unroll
    for(int dy=0;dy<3;dy++)
      #pragma unroll
      for(int dx=0;dx<3;dx++)
        s1 = fmaf(v1s[(c*3+dy)*3+dx], h1s[c][yy+dy][xx+dx], s1);
  }
  int gl = l0 + yy, gn = n0 + xx;
  h2[((size_t)b*LL + gl)*NN + gn] = 0.5f*(s0 + s1 + vb);
}

// ---------------- K14: co = x + h2^T ----------------
__global__ void k_co(const float* __restrict__ x, const float* __restrict__ h2, float* __restrict__ co){
  int n = blockIdx.x, b = blockIdx.y;
  size_t ro = ((size_t)b*NN + n)*LL;
  for(int l=threadIdx.x; l<LL; l+=256)
    co[ro + l] = x[ro + l] + h2[((size_t)b*LL + l)*NN + n];
}

// ---------------- K15: naive GEMM2 + de-normalize epilogue (f32 output!) ----------------
__global__ __launch_bounds__(256) void k_gemm2(const float* __restrict__ co, const float* __restrict__ ldw,
    const float* __restrict__ ldb, const float* __restrict__ mean, const float* __restrict__ stdev,
    float* __restrict__ out){
  __shared__ float cr[LL];
  int row = blockIdx.x;           // 0..2047
  int b = row >> 7, n = row & 127;
  int tid = threadIdx.x;          // p
  for(int l=tid;l<LL;l+=256) cr[l] = co[(size_t)row*LL + l];
  __syncthreads();
  float acc = 0.f;
  const float* wp = ldw + (size_t)tid*LL;
  for(int l=0;l<LL;l++) acc = fmaf(cr[l], wp[l], acc);
  float v = (acc + ldb[tid])*stdev[row] + mean[row];
  out[((size_t)b*PREDN + tid)*NN + n] = v;
}

extern "C" void kernel_launch(void* const* d_in, const int* in_sizes, int n_in,
                              void* d_out, int out_size, void* d_ws, size_t ws_size,
                              hipStream_t stream){
  (void)in_sizes; (void)n_in; (void)out_size; (void)ws_size;
  const float* batch_x = (const float*)d_in[0];
  const float* le_w  = (const float*)d_in[4];
  const float* le_b  = (const float*)d_in[5];
  const float* c1_w  = (const float*)d_in[6];
  const float* c1_b  = (const float*)d_in[7];
  const float* bn1_g = (const float*)d_in[8];
  const float* bn1_b = (const float*)d_in[9];
  const float* c2_w  = (const float*)d_in[10];
  const float* c2_b  = (const float*)d_in[11];
  const float* bn2_g = (const float*)d_in[12];
  const float* bn2_b = (const float*)d_in[13];
  const float* i1_w0 = (const float*)d_in[14];
  const float* i1_b0 = (const float*)d_in[15];
  const float* i1_w1 = (const float*)d_in[16];
  const float* i1_b1 = (const float*)d_in[17];
  const float* i2_w0 = (const float*)d_in[18];
  const float* i2_b0 = (const float*)d_in[19];
  const float* i2_w1 = (const float*)d_in[20];
  const float* i2_b1 = (const float*)d_in[21];
  const float* ld_w  = (const float*)d_in[22];
  const float* ld_b  = (const float*)d_in[23];
  float* out = (float*)d_out;   // reference output dtype is float32

  float* ws   = (float*)d_ws;
  float* mean = ws;                      // 2048
  float* stdev= mean + 2048;             // 2048
  float* rstd = stdev + 2048;            // 2048
  float* xn   = rstd + 2048;             // 1,048,576
  float* x    = xn + (size_t)BB*TT*NN;   // 1,572,864
  float* a    = x + (size_t)BB*NN*LL;    // 4,718,592
  float* t1   = a + (size_t)BB*3*LL*NN;  // 131,072
  float* t1t  = t1 + (size_t)BB*NN*64;   // 131,072
  float* sc1  = t1t + (size_t)BB*64*NN;  // 128
  float* sh1  = sc1 + NN;                // 128
  float* Msp1 = sh1 + NN;                // 131,072
  float* t2   = Msp1 + (size_t)BB*64*NN; // 32,768
  float* t2t  = t2 + (size_t)BB*NN*16;   // 32,768
  float* sc2  = t2t + (size_t)BB*16*NN;  // 128
  float* sh2  = sc2 + NN;                // 128
  float* Msp2 = sh2 + NN;                // 32,768
  float* h2   = Msp2 + (size_t)BB*16*NN; // 1,572,864
  float* co   = a;                       // alias: a dead after k_fusedconv

  k_stats<<<BB, NN, 0, stream>>>(batch_x, mean, stdev, rstd);
  k_xn<<<dim3(TT,BB), NN, 0, stream>>>(batch_x, mean, rstd, xn);
  k_gemm1<<<2048, 256, 0, stream>>>(xn, le_w, le_b, x);
  k_a0<<<dim3(LL,BB), NN, 0, stream>>>(x, a);
  k_conv1<<<dim3(64,BB), NN, 0, stream>>>(x, c1_w, c1_b, t1);
  k_bnstats<<<NN, 256, 0, stream>>>(t1, bn1_g, bn1_b, BB, 64, sc1, sh1);
  k_bnelu_t<<<dim3(64,BB), NN, 0, stream>>>(t1, sc1, sh1, 64, t1t);
  k_spline_solve<64><<<BB, NN, 0, stream>>>(t1t, Msp1);
  k_spline_eval<64><<<dim3(LL,BB), NN, 0, stream>>>(t1t, Msp1, a, 1);
  k_conv2<<<dim3(16,BB), NN, 0, stream>>>(t1t, c2_w, c2_b, t2);
  k_bnstats<<<NN, 256, 0, stream>>>(t2, bn2_g, bn2_b, BB, 16, sc2, sh2);
  k_bnelu_t<<<dim3(16,BB), NN, 0, stream>>>(t2, sc2, sh2, 16, t2t);
  k_spline_solve<16><<<BB, NN, 0, stream>>>(t2t, Msp2);
  k_spline_eval<16><<<dim3(LL,BB), NN, 0, stream>>>(t2t, Msp2, a, 2);
  k_fusedconv<<<dim3(LL/8, NN/32, BB), 256, 0, stream>>>(a, i1_w0, i1_b0, i1_w1, i1_b1,
                                                         i2_w0, i2_b0, i2_w1, i2_b1, h2);
  k_co<<<dim3(NN,BB), 256, 0, stream>>>(x, h2, co);
  k_gemm2<<<2048, 256, 0, stream>>>(co, ld_w, ld_b, mean, stdev, out);
}

// Round 5
// 731.434 us; speedup vs baseline: 1.7068x; 1.7068x over previous
//
#include <hip/hip_runtime.h>
#include <hip/hip_bf16.h>
#include <math.h>

#define BB 16
#define TT 512
#define NN 128
#define PREDN 256
#define DMC 32
#define LL 768
constexpr float EPSF = 1e-5f;

// ---------------- K0: per-(b,n) mean / std over T ----------------
__global__ void k_stats(const float* __restrict__ bx, float* __restrict__ mean,
                        float* __restrict__ stdev, float* __restrict__ rstd){
  int b = blockIdx.x, n = threadIdx.x;
  float s = 0.f, s2 = 0.f;
  const float* p = bx + (size_t)b*TT*NN + n;
  for(int t=0;t<TT;t++){ float v = p[(size_t)t*NN]; s += v; s2 += v*v; }
  float mu = s*(1.f/TT);
  float var = fmaxf(s2*(1.f/TT) - mu*mu, 0.f);
  float sd = sqrtf(var + EPSF);
  int i = b*NN + n;
  mean[i] = mu; stdev[i] = sd; rstd[i] = 1.f/sd;
}

// ---------------- K0b: xn[b,t,n] = (bx - mean)*rstd ----------------
__global__ void k_xn(const float* __restrict__ bx, const float* __restrict__ mean,
                     const float* __restrict__ rstd, float* __restrict__ xn){
  int t = blockIdx.x, b = blockIdx.y, n = threadIdx.x;
  size_t i = ((size_t)b*TT + t)*NN + n;
  int r = b*NN + n;
  xn[i] = (bx[i] - mean[r])*rstd[r];
}

// ---------------- K1: tiled GEMM1  x[row=(b,n)][l] = sum_t xn[b,t,n]*le_w[l,t] + le_b[l]
// 64x64 tile, 256 threads, 4x4 acc/thread
__global__ __launch_bounds__(256) void k_gemm1(const float* __restrict__ xn, const float* __restrict__ lew,
    const float* __restrict__ leb, float* __restrict__ x){
  __shared__ alignas(16) float As[16][68];
  __shared__ alignas(16) float Bs[16][68];
  int tid = threadIdx.x;
  int row0 = blockIdx.x*64, l0 = blockIdx.y*64;
  int b = row0 >> 7, n0 = row0 & 127;
  float acc[4][4] = {};
  int ar = tid & 63, ak = tid >> 6;   // A loader: 64 rows x 4 k-groups
  int bk = tid & 15, bc = tid >> 4;   // B loader: 16 k x 16 col-groups
  int tr = tid & 15, tc = tid >> 4;
  for(int k0=0;k0<TT;k0+=16){
    #pragma unroll
    for(int q=0;q<4;q++){
      int k = ak*4 + q;
      As[k][ar] = xn[((size_t)b*TT + k0 + k)*NN + n0 + ar];
    }
    #pragma unroll
    for(int q=0;q<4;q++){
      int c = bc + 16*q;
      Bs[bk][c] = lew[(size_t)(l0+c)*TT + k0 + bk];
    }
    __syncthreads();
    #pragma unroll
    for(int kk=0;kk<16;kk++){
      float4 av = *(const float4*)&As[kk][4*tr];
      float4 bv = *(const float4*)&Bs[kk][4*tc];
      float aa[4] = {av.x, av.y, av.z, av.w};
      float bb[4] = {bv.x, bv.y, bv.z, bv.w};
      #pragma unroll
      for(int i=0;i<4;i++)
        #pragma unroll
        for(int j=0;j<4;j++) acc[i][j] = fmaf(aa[i], bb[j], acc[i][j]);
    }
    __syncthreads();
  }
  #pragma unroll
  for(int i=0;i<4;i++){
    int row = row0 + 4*tr + i;
    int l = l0 + 4*tc;
    float4 st;
    st.x = acc[i][0] + leb[l+0];
    st.y = acc[i][1] + leb[l+1];
    st.z = acc[i][2] + leb[l+2];
    st.w = acc[i][3] + leb[l+3];
    *(float4*)&x[(size_t)row*LL + l] = st;
  }
}

// ---------------- K2: a[:,0,l,n] = x[b,n,l] ----------------
__global__ void k_a0(const float* __restrict__ x, float* __restrict__ a){
  int l = blockIdx.x, b = blockIdx.y, n = threadIdx.x;
  a[(((size_t)b*3 + 0)*LL + l)*NN + n] = x[((size_t)b*NN + n)*LL + l];
}

// ---------------- K3: conv1d stride 12, kernel 12 ----------------
__global__ __launch_bounds__(128) void k_conv1(const float* __restrict__ x, const float* __restrict__ w,
                                               const float* __restrict__ bias, float* __restrict__ t1){
  __shared__ float xs[NN*12];
  int j = blockIdx.x, b = blockIdx.y, o = threadIdx.x;
  for(int i=o;i<NN*12;i+=NN){
    int ci = i/12, k = i%12;
    xs[i] = x[((size_t)b*NN + ci)*LL + j*12 + k];
  }
  __syncthreads();
  float a0 = bias[o], a1 = 0.f, a2 = 0.f, a3 = 0.f;
  const float* wp = w + (size_t)o*NN*12;
  #pragma unroll 4
  for(int i=0;i<NN*12;i+=4){
    a0 = fmaf(xs[i+0], wp[i+0], a0);
    a1 = fmaf(xs[i+1], wp[i+1], a1);
    a2 = fmaf(xs[i+2], wp[i+2], a2);
    a3 = fmaf(xs[i+3], wp[i+3], a3);
  }
  t1[((size_t)b*NN + o)*64 + j] = (a0 + a1) + (a2 + a3);
}

// ---------------- K4: BN stats per channel ----------------
__global__ void k_bnstats(const float* __restrict__ t, const float* __restrict__ g, const float* __restrict__ bb,
                          int Bcnt, int Jcnt, float* __restrict__ scale, float* __restrict__ shift){
  int o = blockIdx.x;
  int tot = Bcnt*Jcnt;
  float s = 0.f, s2 = 0.f;
  for(int i=threadIdx.x; i<tot; i+=blockDim.x){
    int b = i / Jcnt, j = i % Jcnt;
    float v = t[((size_t)b*NN + o)*Jcnt + j];
    s += v; s2 += v*v;
  }
  __shared__ float rs[256], rs2[256];
  rs[threadIdx.x] = s; rs2[threadIdx.x] = s2;
  __syncthreads();
  for(int st=128; st>0; st>>=1){
    if(threadIdx.x < st){ rs[threadIdx.x] += rs[threadIdx.x+st]; rs2[threadIdx.x] += rs2[threadIdx.x+st]; }
    __syncthreads();
  }
  if(threadIdx.x == 0){
    float mu = rs[0]/tot;
    float var = fmaxf(rs2[0]/tot - mu*mu, 0.f);
    float sc = g[o] * rsqrtf(var + EPSF);
    scale[o] = sc; shift[o] = bb[o] - mu*sc;
  }
}

// ---------------- K5: BN apply + ELU + transpose to (B, J, C) ----------------
__global__ void k_bnelu_t(const float* __restrict__ t, const float* __restrict__ scale,
                          const float* __restrict__ shift, int Jcnt, float* __restrict__ tt){
  int j = blockIdx.x, b = blockIdx.y, o = threadIdx.x;
  float v = t[((size_t)b*NN + o)*Jcnt + j]*scale[o] + shift[o];
  v = v > 0.f ? v : (expf(v) - 1.f);
  tt[((size_t)b*Jcnt + j)*NN + o] = v;
}

// ---------------- K6: spline tridiagonal solve (Thomas) ----------------
template<int LK>
__global__ void k_spline_solve(const float* __restrict__ y, float* __restrict__ M){
  constexpr int m = LK-2;
  const float Kc = 6.f*(LK-1)*(LK-1);
  __shared__ float cp[m];
  __shared__ float dp[m][NN];
  int b = blockIdx.x, c = threadIdx.x;
  if(c == 0){
    float cv = 0.25f; cp[0] = cv;
    for(int i=1;i<m;i++){ cv = 1.f/(4.f - cv); cp[i] = cv; }
  }
  __syncthreads();
  const float* yb = y + (size_t)b*LK*NN + c;
  float y0 = yb[0], y1 = yb[NN];
  float dprev = 0.f;
  for(int i=0;i<m;i++){
    float y2 = yb[(size_t)(i+2)*NN];
    float r = (y2 - 2.f*y1 + y0)*Kc;
    float d = (i == 0) ? r*0.25f : (r - dprev)*cp[i];
    dp[i][c] = d; dprev = d;
    y0 = y1; y1 = y2;
  }
  float* Mb = M + (size_t)b*LK*NN + c;
  float xv = dp[m-1][c];
  Mb[(size_t)m*NN] = xv;
  for(int i=m-2;i>=0;i--){
    xv = dp[i][c] - cp[i]*xv;
    Mb[(size_t)(i+1)*NN] = xv;
  }
  Mb[0] = 0.f;
  Mb[(size_t)(LK-1)*NN] = 0.f;
}

// ---------------- K7: spline evaluation -> a[:,ch,l,n] ----------------
template<int LK>
__global__ void k_spline_eval(const float* __restrict__ y, const float* __restrict__ M,
                              float* __restrict__ a, int ch){
  int l = blockIdx.x, b = blockIdx.y, c = threadIdx.x;
  constexpr float hh = 1.f/(LK-1);
  float q = (float)l * (1.f/(LL-1));
  int idx = (int)floorf(q*(LK-1));
  if(idx > LK-2) idx = LK-2;
  float s = q - idx*hh;
  float u = hh - s;
  const float* yb = y + ((size_t)b*LK + idx)*NN + c;
  const float* Mb = M + ((size_t)b*LK + idx)*NN + c;
  float yi = yb[0], yi1 = yb[NN], M0 = Mb[0], M1 = Mb[NN];
  constexpr float hh6 = hh*hh/6.f;
  float val = (M0*u*u*u + M1*s*s*s)*(1.f/(6.f*hh))
            + (yi  - M0*hh6)*(u*(1.f/hh))
            + (yi1 - M1*hh6)*(s*(1.f/hh));
  a[(((size_t)b*3 + ch)*LL + l)*NN + c] = val;
}

// ---------------- K8: conv1d stride 4, kernel 4 (input transposed layout) ----------------
__global__ __launch_bounds__(128) void k_conv2(const float* __restrict__ tt, const float* __restrict__ w,
                                               const float* __restrict__ bias, float* __restrict__ t2){
  __shared__ float ts[4*NN];
  int j = blockIdx.x, b = blockIdx.y, o = threadIdx.x;
  for(int i=o;i<4*NN;i+=NN) ts[i] = tt[((size_t)b*64 + j*4)*NN + i];
  __syncthreads();
  float acc = bias[o];
  const float* wp = w + (size_t)o*NN*4;
  #pragma unroll 4
  for(int ci=0;ci<NN;ci++){
    acc = fmaf(ts[0*NN+ci], wp[ci*4+0], acc);
    acc = fmaf(ts[1*NN+ci], wp[ci*4+1], acc);
    acc = fmaf(ts[2*NN+ci], wp[ci*4+2], acc);
    acc = fmaf(ts[3*NN+ci], wp[ci*4+3], acc);
  }
  t2[((size_t)b*NN + o)*16 + j] = acc;
}

// ---------------- K13: fused conv2d stage (a -> h1(LDS) -> h2), GELU exact ----------------
__global__ __launch_bounds__(256) void k_fusedconv(const float* __restrict__ a,
    const float* __restrict__ w0, const float* __restrict__ b0,
    const float* __restrict__ w1, const float* __restrict__ b1,
    const float* __restrict__ v0, const float* __restrict__ vb0,
    const float* __restrict__ v1, const float* __restrict__ vb1,
    float* __restrict__ h2){
  constexpr int TL = 8, TN = 32;
  __shared__ float as[3][TL+4][TN+4];        // 3 x 12 x 36
  __shared__ float h1s[DMC][TL+2][TN+2];     // 32 x 10 x 34
  __shared__ float w0s[DMC*3], w1s[DMC*27], b0s[DMC], b1s[DMC], v0s[DMC], v1s[DMC*9];
  __shared__ float vb;
  int tid = threadIdx.x;
  for(int i=tid;i<DMC*3;i+=256) w0s[i] = w0[i];
  for(int i=tid;i<DMC*27;i+=256) w1s[i] = w1[i];
  for(int i=tid;i<DMC*9;i+=256) v1s[i] = v1[i];
  if(tid < DMC){ b0s[tid] = b0[tid]; b1s[tid] = b1[tid]; v0s[tid] = v0[tid]; }
  if(tid == 0) vb = vb0[0] + vb1[0];
  int l0 = blockIdx.x*TL, n0 = blockIdx.y*TN, b = blockIdx.z;
  const float* ab = a + (size_t)b*3*LL*NN;
  float* asf = &as[0][0][0];
  for(int i=tid;i<3*(TL+4)*(TN+4);i+=256){
    int ch = i/((TL+4)*(TN+4));
    int rem = i%((TL+4)*(TN+4));
    int yy = rem/(TN+4), xx = rem%(TN+4);
    int gl = l0 + yy - 2, gn = n0 + xx - 2;
    float v = 0.f;
    if(gl >= 0 && gl < LL && gn >= 0 && gn < NN) v = ab[((size_t)ch*LL + gl)*NN + gn];
    asf[i] = v;
  }
  __syncthreads();
  float* h1f = &h1s[0][0][0];
  for(int idx=tid; idx<DMC*(TL+2)*(TN+2); idx+=256){
    int c = idx/((TL+2)*(TN+2));
    int rem = idx%((TL+2)*(TN+2));
    int yy = rem/(TN+2), xx = rem%(TN+2);
    int gl = l0 + yy - 1, gn = n0 + xx - 1;
    float val = 0.f;
    if(gl >= 0 && gl < LL && gn >= 0 && gn < NN){
      float s0 = 0.f;
      #pragma unroll
      for(int ci=0;ci<3;ci++) s0 = fmaf(w0s[c*3+ci], as[ci][yy+1][xx+1], s0);
      float s1 = 0.f;
      #pragma unroll
      for(int ci=0;ci<3;ci++)
        #pragma unroll
        for(int dy=0;dy<3;dy++)
          #pragma unroll
          for(int dx=0;dx<3;dx++)
            s1 = fmaf(w1s[((c*3+ci)*3+dy)*3+dx], as[ci][yy+dy][xx+dx], s1);
      float hv = 0.5f*(s0 + b0s[c] + s1 + b1s[c]);
      val = hv*0.5f*(1.f + erff(hv*0.70710678118654752f));
    }
    h1f[idx] = val;
  }
  __syncthreads();
  int yy = tid >> 5, xx = tid & 31;
  float s0 = 0.f, s1 = 0.f;
  #pragma unroll
  for(int c=0;c<DMC;c++){
    s0 = fmaf(v0s[c], h1s[c][yy+1][xx+1], s0);
    #pragma unroll
    for(int dy=0;dy<3;dy++)
      #pragma unroll
      for(int dx=0;dx<3;dx++)
        s1 = fmaf(v1s[(c*3+dy)*3+dx], h1s[c][yy+dy][xx+dx], s1);
  }
  int gl = l0 + yy, gn = n0 + xx;
  h2[((size_t)b*LL + gl)*NN + gn] = 0.5f*(s0 + s1 + vb);
}

// ---------------- K14: co = x + h2^T ----------------
__global__ void k_co(const float* __restrict__ x, const float* __restrict__ h2, float* __restrict__ co){
  int n = blockIdx.x, b = blockIdx.y;
  size_t ro = ((size_t)b*NN + n)*LL;
  for(int l=threadIdx.x; l<LL; l+=256)
    co[ro + l] = x[ro + l] + h2[((size_t)b*LL + l)*NN + n];
}

// ---------------- K15: tiled GEMM2 + de-normalize epilogue (f32 output) ----------------
// C[row=(b,n)][p] = sum_l co[row][l]*ldw[p][l]; 64x64 tile
__global__ __launch_bounds__(256) void k_gemm2(const float* __restrict__ co, const float* __restrict__ ldw,
    const float* __restrict__ ldb, const float* __restrict__ mean, const float* __restrict__ stdev,
    float* __restrict__ out){
  __shared__ alignas(16) float As[16][68];
  __shared__ alignas(16) float Bs[16][68];
  int tid = threadIdx.x;
  int row0 = blockIdx.x*64, p0 = blockIdx.y*64;
  float acc[4][4] = {};
  int lk = tid & 15, lr = tid >> 4;
  int tr = tid & 15, tc = tid >> 4;
  for(int k0=0;k0<LL;k0+=16){
    #pragma unroll
    for(int q=0;q<4;q++){
      int r = lr + 16*q;
      As[lk][r] = co[(size_t)(row0+r)*LL + k0 + lk];
    }
    #pragma unroll
    for(int q=0;q<4;q++){
      int c = lr + 16*q;
      Bs[lk][c] = ldw[(size_t)(p0+c)*LL + k0 + lk];
    }
    __syncthreads();
    #pragma unroll
    for(int kk=0;kk<16;kk++){
      float4 av = *(const float4*)&As[kk][4*tr];
      float4 bv = *(const float4*)&Bs[kk][4*tc];
      float aa[4] = {av.x, av.y, av.z, av.w};
      float bb[4] = {bv.x, bv.y, bv.z, bv.w};
      #pragma unroll
      for(int i=0;i<4;i++)
        #pragma unroll
        for(int j=0;j<4;j++) acc[i][j] = fmaf(aa[i], bb[j], acc[i][j]);
    }
    __syncthreads();
  }
  #pragma unroll
  for(int i=0;i<4;i++){
    int row = row0 + 4*tr + i;
    int b = row >> 7, n = row & 127;
    float sd = stdev[row], mu = mean[row];
    #pragma unroll
    for(int j=0;j<4;j++){
      int p = p0 + 4*tc + j;
      float v = (acc[i][j] + ldb[p])*sd + mu;
      out[((size_t)b*PREDN + p)*NN + n] = v;
    }
  }
}

extern "C" void kernel_launch(void* const* d_in, const int* in_sizes, int n_in,
                              void* d_out, int out_size, void* d_ws, size_t ws_size,
                              hipStream_t stream){
  (void)in_sizes; (void)n_in; (void)out_size; (void)ws_size;
  const float* batch_x = (const float*)d_in[0];
  const float* le_w  = (const float*)d_in[4];
  const float* le_b  = (const float*)d_in[5];
  const float* c1_w  = (const float*)d_in[6];
  const float* c1_b  = (const float*)d_in[7];
  const float* bn1_g = (const float*)d_in[8];
  const float* bn1_b = (const float*)d_in[9];
  const float* c2_w  = (const float*)d_in[10];
  const float* c2_b  = (const float*)d_in[11];
  const float* bn2_g = (const float*)d_in[12];
  const float* bn2_b = (const float*)d_in[13];
  const float* i1_w0 = (const float*)d_in[14];
  const float* i1_b0 = (const float*)d_in[15];
  const float* i1_w1 = (const float*)d_in[16];
  const float* i1_b1 = (const float*)d_in[17];
  const float* i2_w0 = (const float*)d_in[18];
  const float* i2_b0 = (const float*)d_in[19];
  const float* i2_w1 = (const float*)d_in[20];
  const float* i2_b1 = (const float*)d_in[21];
  const float* ld_w  = (const float*)d_in[22];
  const float* ld_b  = (const float*)d_in[23];
  float* out = (float*)d_out;

  float* ws   = (float*)d_ws;
  float* mean = ws;                      // 2048
  float* stdev= mean + 2048;             // 2048
  float* rstd = stdev + 2048;            // 2048
  float* xn   = rstd + 2048;             // 1,048,576
  float* x    = xn + (size_t)BB*TT*NN;   // 1,572,864
  float* a    = x + (size_t)BB*NN*LL;    // 4,718,592
  float* t1   = a + (size_t)BB*3*LL*NN;  // 131,072
  float* t1t  = t1 + (size_t)BB*NN*64;   // 131,072
  float* sc1  = t1t + (size_t)BB*64*NN;  // 128
  float* sh1  = sc1 + NN;                // 128
  float* Msp1 = sh1 + NN;                // 131,072
  float* t2   = Msp1 + (size_t)BB*64*NN; // 32,768
  float* t2t  = t2 + (size_t)BB*NN*16;   // 32,768
  float* sc2  = t2t + (size_t)BB*16*NN;  // 128
  float* sh2  = sc2 + NN;                // 128
  float* Msp2 = sh2 + NN;                // 32,768
  float* h2   = Msp2 + (size_t)BB*16*NN; // 1,572,864
  float* co   = a;                       // alias: a dead after k_fusedconv

  k_stats<<<BB, NN, 0, stream>>>(batch_x, mean, stdev, rstd);
  k_xn<<<dim3(TT,BB), NN, 0, stream>>>(batch_x, mean, rstd, xn);
  k_gemm1<<<dim3(32,12), 256, 0, stream>>>(xn, le_w, le_b, x);
  k_a0<<<dim3(LL,BB), NN, 0, stream>>>(x, a);
  k_conv1<<<dim3(64,BB), NN, 0, stream>>>(x, c1_w, c1_b, t1);
  k_bnstats<<<NN, 256, 0, stream>>>(t1, bn1_g, bn1_b, BB, 64, sc1, sh1);
  k_bnelu_t<<<dim3(64,BB), NN, 0, stream>>>(t1, sc1, sh1, 64, t1t);
  k_spline_solve<64><<<BB, NN, 0, stream>>>(t1t, Msp1);
  k_spline_eval<64><<<dim3(LL,BB), NN, 0, stream>>>(t1t, Msp1, a, 1);
  k_conv2<<<dim3(16,BB), NN, 0, stream>>>(t1t, c2_w, c2_b, t2);
  k_bnstats<<<NN, 256, 0, stream>>>(t2, bn2_g, bn2_b, BB, 16, sc2, sh2);
  k_bnelu_t<<<dim3(16,BB), NN, 0, stream>>>(t2, sc2, sh2, 16, t2t);
  k_spline_solve<16><<<BB, NN, 0, stream>>>(t2t, Msp2);
  k_spline_eval<16><<<dim3(LL,BB), NN, 0, stream>>>(t2t, Msp2, a, 2);
  k_fusedconv<<<dim3(LL/8, NN/32, BB), 256, 0, stream>>>(a, i1_w0, i1_b0, i1_w1, i1_b1,
                                                         i2_w0, i2_b0, i2_w1, i2_b1, h2);
  k_co<<<dim3(NN,BB), 256, 0, stream>>>(x, h2, co);
  k_gemm2<<<dim3(32,4), 256, 0, stream>>>(co, ld_w, ld_b, mean, stdev, out);
}

// Round 6
// 484.859 us; speedup vs baseline: 2.5748x; 1.5085x over previous
//
#include <hip/hip_runtime.h>
#include <hip/hip_bf16.h>
#include <math.h>

#define BB 16
#define TT 512
#define NN 128
#define PREDN 256
#define DMC 32
#define LL 768
constexpr float EPSF = 1e-5f;

// ---------------- K0: per-(b,n) mean / std over T ----------------
__global__ void k_stats(const float* __restrict__ bx, float* __restrict__ mean,
                        float* __restrict__ stdev, float* __restrict__ rstd){
  int b = blockIdx.x, n = threadIdx.x;
  float s = 0.f, s2 = 0.f;
  const float* p = bx + (size_t)b*TT*NN + n;
  for(int t=0;t<TT;t++){ float v = p[(size_t)t*NN]; s += v; s2 += v*v; }
  float mu = s*(1.f/TT);
  float var = fmaxf(s2*(1.f/TT) - mu*mu, 0.f);
  float sd = sqrtf(var + EPSF);
  int i = b*NN + n;
  mean[i] = mu; stdev[i] = sd; rstd[i] = 1.f/sd;
}

// ---------------- K0b: xn[b,t,n] = (bx - mean)*rstd ----------------
__global__ void k_xn(const float* __restrict__ bx, const float* __restrict__ mean,
                     const float* __restrict__ rstd, float* __restrict__ xn){
  int t = blockIdx.x, b = blockIdx.y, n = threadIdx.x;
  size_t i = ((size_t)b*TT + t)*NN + n;
  int r = b*NN + n;
  xn[i] = (bx[i] - mean[r])*rstd[r];
}

// ---------------- K1: tiled GEMM1 ----------------
__global__ __launch_bounds__(256) void k_gemm1(const float* __restrict__ xn, const float* __restrict__ lew,
    const float* __restrict__ leb, float* __restrict__ x){
  __shared__ alignas(16) float As[16][68];
  __shared__ alignas(16) float Bs[16][68];
  int tid = threadIdx.x;
  int row0 = blockIdx.x*64, l0 = blockIdx.y*64;
  int b = row0 >> 7, n0 = row0 & 127;
  float acc[4][4] = {};
  int ar = tid & 63, ak = tid >> 6;
  int bk = tid & 15, bc = tid >> 4;
  int tr = tid & 15, tc = tid >> 4;
  for(int k0=0;k0<TT;k0+=16){
    #pragma unroll
    for(int q=0;q<4;q++){
      int k = ak*4 + q;
      As[k][ar] = xn[((size_t)b*TT + k0 + k)*NN + n0 + ar];
    }
    #pragma unroll
    for(int q=0;q<4;q++){
      int c = bc + 16*q;
      Bs[bk][c] = lew[(size_t)(l0+c)*TT + k0 + bk];
    }
    __syncthreads();
    #pragma unroll
    for(int kk=0;kk<16;kk++){
      float4 av = *(const float4*)&As[kk][4*tr];
      float4 bv = *(const float4*)&Bs[kk][4*tc];
      float aa[4] = {av.x, av.y, av.z, av.w};
      float bb[4] = {bv.x, bv.y, bv.z, bv.w};
      #pragma unroll
      for(int i=0;i<4;i++)
        #pragma unroll
        for(int j=0;j<4;j++) acc[i][j] = fmaf(aa[i], bb[j], acc[i][j]);
    }
    __syncthreads();
  }
  #pragma unroll
  for(int i=0;i<4;i++){
    int row = row0 + 4*tr + i;
    int l = l0 + 4*tc;
    float4 st;
    st.x = acc[i][0] + leb[l+0];
    st.y = acc[i][1] + leb[l+1];
    st.z = acc[i][2] + leb[l+2];
    st.w = acc[i][3] + leb[l+3];
    *(float4*)&x[(size_t)row*LL + l] = st;
  }
}

// ---------------- K2: a[:,0,l,n] = x[b,n,l] ----------------
__global__ void k_a0(const float* __restrict__ x, float* __restrict__ a){
  int l = blockIdx.x, b = blockIdx.y, n = threadIdx.x;
  a[(((size_t)b*3 + 0)*LL + l)*NN + n] = x[((size_t)b*NN + n)*LL + l];
}

// ---------------- K3: conv1d stride 12, kernel 12 ----------------
__global__ __launch_bounds__(128) void k_conv1(const float* __restrict__ x, const float* __restrict__ w,
                                               const float* __restrict__ bias, float* __restrict__ t1){
  __shared__ float xs[NN*12];
  int j = blockIdx.x, b = blockIdx.y, o = threadIdx.x;
  for(int i=o;i<NN*12;i+=NN){
    int ci = i/12, k = i%12;
    xs[i] = x[((size_t)b*NN + ci)*LL + j*12 + k];
  }
  __syncthreads();
  float a0 = bias[o], a1 = 0.f, a2 = 0.f, a3 = 0.f;
  const float* wp = w + (size_t)o*NN*12;
  #pragma unroll 4
  for(int i=0;i<NN*12;i+=4){
    a0 = fmaf(xs[i+0], wp[i+0], a0);
    a1 = fmaf(xs[i+1], wp[i+1], a1);
    a2 = fmaf(xs[i+2], wp[i+2], a2);
    a3 = fmaf(xs[i+3], wp[i+3], a3);
  }
  t1[((size_t)b*NN + o)*64 + j] = (a0 + a1) + (a2 + a3);
}

// ---------------- K4: BN stats per channel ----------------
__global__ void k_bnstats(const float* __restrict__ t, const float* __restrict__ g, const float* __restrict__ bb,
                          int Bcnt, int Jcnt, float* __restrict__ scale, float* __restrict__ shift){
  int o = blockIdx.x;
  int tot = Bcnt*Jcnt;
  float s = 0.f, s2 = 0.f;
  for(int i=threadIdx.x; i<tot; i+=blockDim.x){
    int b = i / Jcnt, j = i % Jcnt;
    float v = t[((size_t)b*NN + o)*Jcnt + j];
    s += v; s2 += v*v;
  }
  __shared__ float rs[256], rs2[256];
  rs[threadIdx.x] = s; rs2[threadIdx.x] = s2;
  __syncthreads();
  for(int st=128; st>0; st>>=1){
    if(threadIdx.x < st){ rs[threadIdx.x] += rs[threadIdx.x+st]; rs2[threadIdx.x] += rs2[threadIdx.x+st]; }
    __syncthreads();
  }
  if(threadIdx.x == 0){
    float mu = rs[0]/tot;
    float var = fmaxf(rs2[0]/tot - mu*mu, 0.f);
    float sc = g[o] * rsqrtf(var + EPSF);
    scale[o] = sc; shift[o] = bb[o] - mu*sc;
  }
}

// ---------------- K5: BN apply + ELU + transpose ----------------
__global__ void k_bnelu_t(const float* __restrict__ t, const float* __restrict__ scale,
                          const float* __restrict__ shift, int Jcnt, float* __restrict__ tt){
  int j = blockIdx.x, b = blockIdx.y, o = threadIdx.x;
  float v = t[((size_t)b*NN + o)*Jcnt + j]*scale[o] + shift[o];
  v = v > 0.f ? v : (expf(v) - 1.f);
  tt[((size_t)b*Jcnt + j)*NN + o] = v;
}

// ---------------- K6: spline tridiagonal solve (Thomas) ----------------
template<int LK>
__global__ void k_spline_solve(const float* __restrict__ y, float* __restrict__ M){
  constexpr int m = LK-2;
  const float Kc = 6.f*(LK-1)*(LK-1);
  __shared__ float cp[m];
  __shared__ float dp[m][NN];
  int b = blockIdx.x, c = threadIdx.x;
  if(c == 0){
    float cv = 0.25f; cp[0] = cv;
    for(int i=1;i<m;i++){ cv = 1.f/(4.f - cv); cp[i] = cv; }
  }
  __syncthreads();
  const float* yb = y + (size_t)b*LK*NN + c;
  float y0 = yb[0], y1 = yb[NN];
  float dprev = 0.f;
  for(int i=0;i<m;i++){
    float y2 = yb[(size_t)(i+2)*NN];
    float r = (y2 - 2.f*y1 + y0)*Kc;
    float d = (i == 0) ? r*0.25f : (r - dprev)*cp[i];
    dp[i][c] = d; dprev = d;
    y0 = y1; y1 = y2;
  }
  float* Mb = M + (size_t)b*LK*NN + c;
  float xv = dp[m-1][c];
  Mb[(size_t)m*NN] = xv;
  for(int i=m-2;i>=0;i--){
    xv = dp[i][c] - cp[i]*xv;
    Mb[(size_t)(i+1)*NN] = xv;
  }
  Mb[0] = 0.f;
  Mb[(size_t)(LK-1)*NN] = 0.f;
}

// ---------------- K7: spline evaluation ----------------
template<int LK>
__global__ void k_spline_eval(const float* __restrict__ y, const float* __restrict__ M,
                              float* __restrict__ a, int ch){
  int l = blockIdx.x, b = blockIdx.y, c = threadIdx.x;
  constexpr float hh = 1.f/(LK-1);
  float q = (float)l * (1.f/(LL-1));
  int idx = (int)floorf(q*(LK-1));
  if(idx > LK-2) idx = LK-2;
  float s = q - idx*hh;
  float u = hh - s;
  const float* yb = y + ((size_t)b*LK + idx)*NN + c;
  const float* Mb = M + ((size_t)b*LK + idx)*NN + c;
  float yi = yb[0], yi1 = yb[NN], M0 = Mb[0], M1 = Mb[NN];
  constexpr float hh6 = hh*hh/6.f;
  float val = (M0*u*u*u + M1*s*s*s)*(1.f/(6.f*hh))
            + (yi  - M0*hh6)*(u*(1.f/hh))
            + (yi1 - M1*hh6)*(s*(1.f/hh));
  a[(((size_t)b*3 + ch)*LL + l)*NN + c] = val;
}

// ---------------- K8: conv1d stride 4, kernel 4 ----------------
__global__ __launch_bounds__(128) void k_conv2(const float* __restrict__ tt, const float* __restrict__ w,
                                               const float* __restrict__ bias, float* __restrict__ t2){
  __shared__ float ts[4*NN];
  int j = blockIdx.x, b = blockIdx.y, o = threadIdx.x;
  for(int i=o;i<4*NN;i+=NN) ts[i] = tt[((size_t)b*64 + j*4)*NN + i];
  __syncthreads();
  float acc = bias[o];
  const float* wp = w + (size_t)o*NN*4;
  #pragma unroll 4
  for(int ci=0;ci<NN;ci++){
    acc = fmaf(ts[0*NN+ci], wp[ci*4+0], acc);
    acc = fmaf(ts[1*NN+ci], wp[ci*4+1], acc);
    acc = fmaf(ts[2*NN+ci], wp[ci*4+2], acc);
    acc = fmaf(ts[3*NN+ci], wp[ci*4+3], acc);
  }
  t2[((size_t)b*NN + o)*16 + j] = acc;
}

// ---------------- K13: fused conv2d stage, restructured ----------------
// stage1: thread = (c = tid&31, quad-group = tid>>5); weights in registers
// stage2: thread = output pixel; weights via uniform float4 broadcast
__global__ __launch_bounds__(256) void k_fusedconv(const float* __restrict__ a,
    const float* __restrict__ w0, const float* __restrict__ b0,
    const float* __restrict__ w1, const float* __restrict__ b1,
    const float* __restrict__ v0, const float* __restrict__ vb0,
    const float* __restrict__ v1, const float* __restrict__ vb1,
    float* __restrict__ h2){
  constexpr int TL = 8, TN = 32;
  constexpr int AY = TL+4, AX = 40;      // a tile rows 12, padded cols 40 (valid 36)
  constexpr int HY = TL+2, HX = TN+2;    // h1 valid 10 x 34
  constexpr int HXP = 35;                // pad: stride HY*HXP=350 dwords -> 2-way store alias (free)
  __shared__ alignas(16) float as[3][AY][AX];   // 5.76 KB
  __shared__ float h1s[DMC][HY][HXP];           // 44.8 KB
  __shared__ alignas(16) float vws[9*DMC];      // 1.15 KB
  __shared__ float vbs;
  int tid = threadIdx.x;
  int l0 = blockIdx.x*TL, n0 = blockIdx.y*TN, b = blockIdx.z;

  // ---- stage 0: stage a tile (zero-padded) ----
  const float* ab = a + (size_t)b*3*LL*NN;
  float* asf = &as[0][0][0];
  for(int i=tid;i<3*AY*AX;i+=256){
    int ch = i/(AY*AX), rem = i%(AY*AX), yy = rem/AX, xx = rem%AX;
    int gl = l0 + yy - 2, gn = n0 + xx - 2;
    float v = 0.f;
    if(gl >= 0 && gl < LL && gn >= 0 && gn < NN) v = ab[((size_t)ch*LL + gl)*NN + gn];
    asf[i] = v;
  }
  // ---- build folded stage-2 weights ----
  for(int i=tid;i<9*DMC;i+=256){
    int tap = i/DMC, c2 = i%DMC;
    float wv = 0.5f*v1[c2*9 + tap];
    if(tap == 4) wv += 0.5f*v0[c2];
    vws[tap*DMC + c2] = wv;
  }
  if(tid == 0) vbs = vb0[0] + vb1[0];

  // ---- stage-1 weights into registers (folded 1x1 into 3x3 center) ----
  int c = tid & 31, qg = tid >> 5;
  float wr[3][3][3];
  #pragma unroll
  for(int ci=0;ci<3;ci++)
    #pragma unroll
    for(int dy=0;dy<3;dy++)
      #pragma unroll
      for(int dx=0;dx<3;dx++){
        float wv = 0.5f*w1[((c*3+ci)*3+dy)*3+dx];
        if(dy==1 && dx==1) wv += 0.5f*w0[c*3+ci];
        wr[ci][dy][dx] = wv;
      }
  float br = 0.5f*(b0[c] + b1[c]);
  __syncthreads();

  // ---- stage 1: h1 = GELU(conv3x3(a, w_comb) + br), 4 pixels/iter ----
  // quads: 10 rows x 9 x-quads = 90; qg in [0,8) strides them
  for(int q=qg; q<90; q+=8){
    int yy = q/9, x0 = (q%9)*4;
    float win[3][3][6];
    #pragma unroll
    for(int ci=0;ci<3;ci++)
      #pragma unroll
      for(int dy=0;dy<3;dy++){
        float4 r4 = *(const float4*)&as[ci][yy+dy][x0];
        float2 r2 = *(const float2*)&as[ci][yy+dy][x0+4];
        win[ci][dy][0]=r4.x; win[ci][dy][1]=r4.y; win[ci][dy][2]=r4.z;
        win[ci][dy][3]=r4.w; win[ci][dy][4]=r2.x; win[ci][dy][5]=r2.y;
      }
    #pragma unroll
    for(int p=0;p<4;p++){
      int xx = x0 + p;
      if(xx >= HX) continue;
      int gl = l0 + yy - 1, gn = n0 + xx - 1;
      float val = 0.f;
      if(gl >= 0 && gl < LL && gn >= 0 && gn < NN){
        float s = br;
        #pragma unroll
        for(int ci=0;ci<3;ci++)
          #pragma unroll
          for(int dy=0;dy<3;dy++)
            #pragma unroll
            for(int dx=0;dx<3;dx++)
              s = fmaf(wr[ci][dy][dx], win[ci][dy][p+dx], s);
        val = s*0.5f*(1.f + erff(s*0.70710678118654752f));
      }
      h1s[c][yy][xx] = val;
    }
  }
  __syncthreads();

  // ---- stage 2: h2 = conv3x3_32ch(h1, v_comb) + vbs ----
  int oy = tid >> 5, ox = tid & 31;
  float acc = 0.f;
  #pragma unroll
  for(int dy=0;dy<3;dy++)
    #pragma unroll
    for(int dx=0;dx<3;dx++){
      int tap = dy*3 + dx;
      #pragma unroll
      for(int cg=0;cg<8;cg++){
        float4 wv = *(const float4*)&vws[tap*DMC + cg*4];
        float h0v = h1s[cg*4+0][oy+dy][ox+dx];
        float h1v = h1s[cg*4+1][oy+dy][ox+dx];
        float h2v = h1s[cg*4+2][oy+dy][ox+dx];
        float h3v = h1s[cg*4+3][oy+dy][ox+dx];
        acc = fmaf(h0v, wv.x, acc);
        acc = fmaf(h1v, wv.y, acc);
        acc = fmaf(h2v, wv.z, acc);
        acc = fmaf(h3v, wv.w, acc);
      }
    }
  int gl = l0 + oy, gn = n0 + ox;
  h2[((size_t)b*LL + gl)*NN + gn] = acc + vbs;
}

// ---------------- K14: co = x + h2^T ----------------
__global__ void k_co(const float* __restrict__ x, const float* __restrict__ h2, float* __restrict__ co){
  int n = blockIdx.x, b = blockIdx.y;
  size_t ro = ((size_t)b*NN + n)*LL;
  for(int l=threadIdx.x; l<LL; l+=256)
    co[ro + l] = x[ro + l] + h2[((size_t)b*LL + l)*NN + n];
}

// ---------------- K15: tiled GEMM2 + de-normalize epilogue ----------------
__global__ __launch_bounds__(256) void k_gemm2(const float* __restrict__ co, const float* __restrict__ ldw,
    const float* __restrict__ ldb, const float* __restrict__ mean, const float* __restrict__ stdev,
    float* __restrict__ out){
  __shared__ alignas(16) float As[16][68];
  __shared__ alignas(16) float Bs[16][68];
  int tid = threadIdx.x;
  int row0 = blockIdx.x*64, p0 = blockIdx.y*64;
  float acc[4][4] = {};
  int lk = tid & 15, lr = tid >> 4;
  int tr = tid & 15, tc = tid >> 4;
  for(int k0=0;k0<LL;k0+=16){
    #pragma unroll
    for(int q=0;q<4;q++){
      int r = lr + 16*q;
      As[lk][r] = co[(size_t)(row0+r)*LL + k0 + lk];
    }
    #pragma unroll
    for(int q=0;q<4;q++){
      int cc = lr + 16*q;
      Bs[lk][cc] = ldw[(size_t)(p0+cc)*LL + k0 + lk];
    }
    __syncthreads();
    #pragma unroll
    for(int kk=0;kk<16;kk++){
      float4 av = *(const float4*)&As[kk][4*tr];
      float4 bv = *(const float4*)&Bs[kk][4*tc];
      float aa[4] = {av.x, av.y, av.z, av.w};
      float bb[4] = {bv.x, bv.y, bv.z, bv.w};
      #pragma unroll
      for(int i=0;i<4;i++)
        #pragma unroll
        for(int j=0;j<4;j++) acc[i][j] = fmaf(aa[i], bb[j], acc[i][j]);
    }
    __syncthreads();
  }
  #pragma unroll
  for(int i=0;i<4;i++){
    int row = row0 + 4*tr + i;
    int b = row >> 7, n = row & 127;
    float sd = stdev[row], mu = mean[row];
    #pragma unroll
    for(int j=0;j<4;j++){
      int p = p0 + 4*tc + j;
      float v = (acc[i][j] + ldb[p])*sd + mu;
      out[((size_t)b*PREDN + p)*NN + n] = v;
    }
  }
}

extern "C" void kernel_launch(void* const* d_in, const int* in_sizes, int n_in,
                              void* d_out, int out_size, void* d_ws, size_t ws_size,
                              hipStream_t stream){
  (void)in_sizes; (void)n_in; (void)out_size; (void)ws_size;
  const float* batch_x = (const float*)d_in[0];
  const float* le_w  = (const float*)d_in[4];
  const float* le_b  = (const float*)d_in[5];
  const float* c1_w  = (const float*)d_in[6];
  const float* c1_b  = (const float*)d_in[7];
  const float* bn1_g = (const float*)d_in[8];
  const float* bn1_b = (const float*)d_in[9];
  const float* c2_w  = (const float*)d_in[10];
  const float* c2_b  = (const float*)d_in[11];
  const float* bn2_g = (const float*)d_in[12];
  const float* bn2_b = (const float*)d_in[13];
  const float* i1_w0 = (const float*)d_in[14];
  const float* i1_b0 = (const float*)d_in[15];
  const float* i1_w1 = (const float*)d_in[16];
  const float* i1_b1 = (const float*)d_in[17];
  const float* i2_w0 = (const float*)d_in[18];
  const float* i2_b0 = (const float*)d_in[19];
  const float* i2_w1 = (const float*)d_in[20];
  const float* i2_b1 = (const float*)d_in[21];
  const float* ld_w  = (const float*)d_in[22];
  const float* ld_b  = (const float*)d_in[23];
  float* out = (float*)d_out;

  float* ws   = (float*)d_ws;
  float* mean = ws;                      // 2048
  float* stdev= mean + 2048;             // 2048
  float* rstd = stdev + 2048;            // 2048
  float* xn   = rstd + 2048;             // 1,048,576
  float* x    = xn + (size_t)BB*TT*NN;   // 1,572,864
  float* a    = x + (size_t)BB*NN*LL;    // 4,718,592
  float* t1   = a + (size_t)BB*3*LL*NN;  // 131,072
  float* t1t  = t1 + (size_t)BB*NN*64;   // 131,072
  float* sc1  = t1t + (size_t)BB*64*NN;  // 128
  float* sh1  = sc1 + NN;                // 128
  float* Msp1 = sh1 + NN;                // 131,072
  float* t2   = Msp1 + (size_t)BB*64*NN; // 32,768
  float* t2t  = t2 + (size_t)BB*NN*16;   // 32,768
  float* sc2  = t2t + (size_t)BB*16*NN;  // 128
  float* sh2  = sc2 + NN;                // 128
  float* Msp2 = sh2 + NN;                // 32,768
  float* h2   = Msp2 + (size_t)BB*16*NN; // 1,572,864
  float* co   = a;                       // alias: a dead after k_fusedconv

  k_stats<<<BB, NN, 0, stream>>>(batch_x, mean, stdev, rstd);
  k_xn<<<dim3(TT,BB), NN, 0, stream>>>(batch_x, mean, rstd, xn);
  k_gemm1<<<dim3(32,12), 256, 0, stream>>>(xn, le_w, le_b, x);
  k_a0<<<dim3(LL,BB), NN, 0, stream>>>(x, a);
  k_conv1<<<dim3(64,BB), NN, 0, stream>>>(x, c1_w, c1_b, t1);
  k_bnstats<<<NN, 256, 0, stream>>>(t1, bn1_g, bn1_b, BB, 64, sc1, sh1);
  k_bnelu_t<<<dim3(64,BB), NN, 0, stream>>>(t1, sc1, sh1, 64, t1t);
  k_spline_solve<64><<<BB, NN, 0, stream>>>(t1t, Msp1);
  k_spline_eval<64><<<dim3(LL,BB), NN, 0, stream>>>(t1t, Msp1, a, 1);
  k_conv2<<<dim3(16,BB), NN, 0, stream>>>(t1t, c2_w, c2_b, t2);
  k_bnstats<<<NN, 256, 0, stream>>>(t2, bn2_g, bn2_b, BB, 16, sc2, sh2);
  k_bnelu_t<<<dim3(16,BB), NN, 0, stream>>>(t2, sc2, sh2, 16, t2t);
  k_spline_solve<16><<<BB, NN, 0, stream>>>(t2t, Msp2);
  k_spline_eval<16><<<dim3(LL,BB), NN, 0, stream>>>(t2t, Msp2, a, 2);
  k_fusedconv<<<dim3(LL/8, NN/32, BB), 256, 0, stream>>>(a, i1_w0, i1_b0, i1_w1, i1_b1,
                                                         i2_w0, i2_b0, i2_w1, i2_b1, h2);
  k_co<<<dim3(NN,BB), 256, 0, stream>>>(x, h2, co);
  k_gemm2<<<dim3(32,4), 256, 0, stream>>>(co, ld_w, ld_b, mean, stdev, out);
}

// Round 7
// 460.288 us; speedup vs baseline: 2.7122x; 1.0534x over previous
//
#include <hip/hip_runtime.h>
#include <hip/hip_bf16.h>
#include <math.h>

#define BB 16
#define TT 512
#define NN 128
#define PREDN 256
#define DMC 32
#define LL 768
constexpr float EPSF = 1e-5f;

// ---------------- K0: per-(b,n) mean / std over T ----------------
__global__ void k_stats(const float* __restrict__ bx, float* __restrict__ mean,
                        float* __restrict__ stdev, float* __restrict__ rstd){
  int b = blockIdx.x, n = threadIdx.x;
  float s = 0.f, s2 = 0.f;
  const float* p = bx + (size_t)b*TT*NN + n;
  for(int t=0;t<TT;t++){ float v = p[(size_t)t*NN]; s += v; s2 += v*v; }
  float mu = s*(1.f/TT);
  float var = fmaxf(s2*(1.f/TT) - mu*mu, 0.f);
  float sd = sqrtf(var + EPSF);
  int i = b*NN + n;
  mean[i] = mu; stdev[i] = sd; rstd[i] = 1.f/sd;
}

// ---------------- K0c: fold stage-2 conv weights -> vwsT[tap][c] ----------------
__global__ void k_prepw(const float* __restrict__ v0, const float* __restrict__ v1,
                        float* __restrict__ vwsT){
  for(int i=threadIdx.x; i<9*DMC; i+=blockDim.x){
    int tap = i/DMC, c = i%DMC;
    float wv = 0.5f*v1[c*9 + tap];
    if(tap == 4) wv += 0.5f*v0[c];
    vwsT[i] = wv;
  }
}

// ---------------- K1: tiled GEMM1 with fused normalization + dual store ----------------
// x[row=(b,n)][l] and a0[b,l,n] = x^T
__global__ __launch_bounds__(256) void k_gemm1(const float* __restrict__ bx, const float* __restrict__ lew,
    const float* __restrict__ leb, const float* __restrict__ mean, const float* __restrict__ rstd,
    float* __restrict__ x, float* __restrict__ a0){
  __shared__ alignas(16) float As[16][68];
  __shared__ alignas(16) float Bs[16][68];
  int tid = threadIdx.x;
  int row0 = blockIdx.x*64, l0 = blockIdx.y*64;
  int b = row0 >> 7, n0 = row0 & 127;
  float acc[4][4] = {};
  int ar = tid & 63, ak = tid >> 6;
  int bk = tid & 15, bc = tid >> 4;
  int tr = tid & 15, tc = tid >> 4;
  float mu_a = mean[row0 + ar];
  float rs_a = rstd[row0 + ar];
  for(int k0=0;k0<TT;k0+=16){
    #pragma unroll
    for(int q=0;q<4;q++){
      int k = ak*4 + q;
      As[k][ar] = (bx[((size_t)b*TT + k0 + k)*NN + n0 + ar] - mu_a)*rs_a;
    }
    #pragma unroll
    for(int q=0;q<4;q++){
      int c = bc + 16*q;
      Bs[bk][c] = lew[(size_t)(l0+c)*TT + k0 + bk];
    }
    __syncthreads();
    #pragma unroll
    for(int kk=0;kk<16;kk++){
      float4 av = *(const float4*)&As[kk][4*tr];
      float4 bv = *(const float4*)&Bs[kk][4*tc];
      float aa[4] = {av.x, av.y, av.z, av.w};
      float bb[4] = {bv.x, bv.y, bv.z, bv.w};
      #pragma unroll
      for(int i=0;i<4;i++)
        #pragma unroll
        for(int j=0;j<4;j++) acc[i][j] = fmaf(aa[i], bb[j], acc[i][j]);
    }
    __syncthreads();
  }
  #pragma unroll
  for(int i=0;i<4;i++){
    int row = row0 + 4*tr + i;
    int l = l0 + 4*tc;
    float4 st;
    st.x = acc[i][0] + leb[l+0];
    st.y = acc[i][1] + leb[l+1];
    st.z = acc[i][2] + leb[l+2];
    st.w = acc[i][3] + leb[l+3];
    *(float4*)&x[(size_t)row*LL + l] = st;
  }
  // transposed store into a channel 0: a0[b][l][n]
  #pragma unroll
  for(int j=0;j<4;j++){
    int l = l0 + 4*tc + j;
    float lb = leb[l];
    float4 st;
    st.x = acc[0][j] + lb;
    st.y = acc[1][j] + lb;
    st.z = acc[2][j] + lb;
    st.w = acc[3][j] + lb;
    *(float4*)&a0[((size_t)b*3*LL + l)*NN + n0 + 4*tr] = st;
  }
}

// ---------------- K3: conv1d stride 12, kernel 12 ----------------
__global__ __launch_bounds__(128) void k_conv1(const float* __restrict__ x, const float* __restrict__ w,
                                               const float* __restrict__ bias, float* __restrict__ t1){
  __shared__ float xs[NN*12];
  int j = blockIdx.x, b = blockIdx.y, o = threadIdx.x;
  for(int i=o;i<NN*12;i+=NN){
    int ci = i/12, k = i%12;
    xs[i] = x[((size_t)b*NN + ci)*LL + j*12 + k];
  }
  __syncthreads();
  float a0 = bias[o], a1 = 0.f, a2 = 0.f, a3 = 0.f;
  const float* wp = w + (size_t)o*NN*12;
  #pragma unroll 4
  for(int i=0;i<NN*12;i+=4){
    a0 = fmaf(xs[i+0], wp[i+0], a0);
    a1 = fmaf(xs[i+1], wp[i+1], a1);
    a2 = fmaf(xs[i+2], wp[i+2], a2);
    a3 = fmaf(xs[i+3], wp[i+3], a3);
  }
  t1[((size_t)b*NN + o)*64 + j] = (a0 + a1) + (a2 + a3);
}

// ---------------- K4: BN stats per channel ----------------
__global__ void k_bnstats(const float* __restrict__ t, const float* __restrict__ g, const float* __restrict__ bb,
                          int Bcnt, int Jcnt, float* __restrict__ scale, float* __restrict__ shift){
  int o = blockIdx.x;
  int tot = Bcnt*Jcnt;
  float s = 0.f, s2 = 0.f;
  for(int i=threadIdx.x; i<tot; i+=blockDim.x){
    int b = i / Jcnt, j = i % Jcnt;
    float v = t[((size_t)b*NN + o)*Jcnt + j];
    s += v; s2 += v*v;
  }
  __shared__ float rs[256], rs2[256];
  rs[threadIdx.x] = s; rs2[threadIdx.x] = s2;
  __syncthreads();
  for(int st=128; st>0; st>>=1){
    if(threadIdx.x < st){ rs[threadIdx.x] += rs[threadIdx.x+st]; rs2[threadIdx.x] += rs2[threadIdx.x+st]; }
    __syncthreads();
  }
  if(threadIdx.x == 0){
    float mu = rs[0]/tot;
    float var = fmaxf(rs2[0]/tot - mu*mu, 0.f);
    float sc = g[o] * rsqrtf(var + EPSF);
    scale[o] = sc; shift[o] = bb[o] - mu*sc;
  }
}

// ---------------- K5: BN apply + ELU + transpose ----------------
__global__ void k_bnelu_t(const float* __restrict__ t, const float* __restrict__ scale,
                          const float* __restrict__ shift, int Jcnt, float* __restrict__ tt){
  int j = blockIdx.x, b = blockIdx.y, o = threadIdx.x;
  float v = t[((size_t)b*NN + o)*Jcnt + j]*scale[o] + shift[o];
  v = v > 0.f ? v : (expf(v) - 1.f);
  tt[((size_t)b*Jcnt + j)*NN + o] = v;
}

// ---------------- K6: spline tridiagonal solve (Thomas) ----------------
template<int LK>
__global__ void k_spline_solve(const float* __restrict__ y, float* __restrict__ M){
  constexpr int m = LK-2;
  const float Kc = 6.f*(LK-1)*(LK-1);
  __shared__ float cp[m];
  __shared__ float dp[m][NN];
  int b = blockIdx.x, c = threadIdx.x;
  if(c == 0){
    float cv = 0.25f; cp[0] = cv;
    for(int i=1;i<m;i++){ cv = 1.f/(4.f - cv); cp[i] = cv; }
  }
  __syncthreads();
  const float* yb = y + (size_t)b*LK*NN + c;
  float y0 = yb[0], y1 = yb[NN];
  float dprev = 0.f;
  for(int i=0;i<m;i++){
    float y2 = yb[(size_t)(i+2)*NN];
    float r = (y2 - 2.f*y1 + y0)*Kc;
    float d = (i == 0) ? r*0.25f : (r - dprev)*cp[i];
    dp[i][c] = d; dprev = d;
    y0 = y1; y1 = y2;
  }
  float* Mb = M + (size_t)b*LK*NN + c;
  float xv = dp[m-1][c];
  Mb[(size_t)m*NN] = xv;
  for(int i=m-2;i>=0;i--){
    xv = dp[i][c] - cp[i]*xv;
    Mb[(size_t)(i+1)*NN] = xv;
  }
  Mb[0] = 0.f;
  Mb[(size_t)(LK-1)*NN] = 0.f;
}

// ---------------- K7: spline evaluation ----------------
template<int LK>
__global__ void k_spline_eval(const float* __restrict__ y, const float* __restrict__ M,
                              float* __restrict__ a, int ch){
  int l = blockIdx.x, b = blockIdx.y, c = threadIdx.x;
  constexpr float hh = 1.f/(LK-1);
  float q = (float)l * (1.f/(LL-1));
  int idx = (int)floorf(q*(LK-1));
  if(idx > LK-2) idx = LK-2;
  float s = q - idx*hh;
  float u = hh - s;
  const float* yb = y + ((size_t)b*LK + idx)*NN + c;
  const float* Mb = M + ((size_t)b*LK + idx)*NN + c;
  float yi = yb[0], yi1 = yb[NN], M0 = Mb[0], M1 = Mb[NN];
  constexpr float hh6 = hh*hh/6.f;
  float val = (M0*u*u*u + M1*s*s*s)*(1.f/(6.f*hh))
            + (yi  - M0*hh6)*(u*(1.f/hh))
            + (yi1 - M1*hh6)*(s*(1.f/hh));
  a[(((size_t)b*3 + ch)*LL + l)*NN + c] = val;
}

// ---------------- K8: conv1d stride 4, kernel 4 ----------------
__global__ __launch_bounds__(128) void k_conv2(const float* __restrict__ tt, const float* __restrict__ w,
                                               const float* __restrict__ bias, float* __restrict__ t2){
  __shared__ float ts[4*NN];
  int j = blockIdx.x, b = blockIdx.y, o = threadIdx.x;
  for(int i=o;i<4*NN;i+=NN) ts[i] = tt[((size_t)b*64 + j*4)*NN + i];
  __syncthreads();
  float acc = bias[o];
  const float* wp = w + (size_t)o*NN*4;
  #pragma unroll 4
  for(int ci=0;ci<NN;ci++){
    acc = fmaf(ts[0*NN+ci], wp[ci*4+0], acc);
    acc = fmaf(ts[1*NN+ci], wp[ci*4+1], acc);
    acc = fmaf(ts[2*NN+ci], wp[ci*4+2], acc);
    acc = fmaf(ts[3*NN+ci], wp[ci*4+3], acc);
  }
  t2[((size_t)b*NN + o)*16 + j] = acc;
}

// ---------------- K13: fused conv2d stage -> writes co_t[b,l,n] = h2 + x^T ----------------
// stage1: thread=(c,quad-group), weights in registers, h1 -> LDS [y][x][c] (c-stride 34)
// stage2: thread=(oy,ox); data float2-over-c from LDS; folded weights float4 from global (VMEM)
__global__ __launch_bounds__(256) void k_fusedconv(const float* __restrict__ a,
    const float* __restrict__ w0, const float* __restrict__ b0,
    const float* __restrict__ w1, const float* __restrict__ b1,
    const float* __restrict__ vwsT, const float* __restrict__ vb0,
    const float* __restrict__ vb1, float* __restrict__ cot){
  constexpr int TL = 8, TN = 32;
  constexpr int AY = TL+4, AX = 40;      // a tile 12 x 40 (valid 36)
  constexpr int HY = TL+2, HX = TN+2;    // h1 10 x 34
  constexpr int CP = 34;                 // c-stride: even (8B align) and ≡2 mod 32 (2-way = free)
  __shared__ alignas(16) float as[3][AY][AX];      // 5.76 KB
  __shared__ alignas(16) float h1s[HY][HX][CP];    // 46.2 KB
  int tid = threadIdx.x;
  int l0 = blockIdx.x*TL, n0 = blockIdx.y*TN, b = blockIdx.z;

  const float* ab = a + (size_t)b*3*LL*NN;
  float* asf = &as[0][0][0];
  for(int i=tid;i<3*AY*AX;i+=256){
    int ch = i/(AY*AX), rem = i%(AY*AX), yy = rem/AX, xx = rem%AX;
    int gl = l0 + yy - 2, gn = n0 + xx - 2;
    float v = 0.f;
    if(gl >= 0 && gl < LL && gn >= 0 && gn < NN) v = ab[((size_t)ch*LL + gl)*NN + gn];
    asf[i] = v;
  }

  int c = tid & 31, qg = tid >> 5;
  float wr[3][3][3];
  #pragma unroll
  for(int ci=0;ci<3;ci++)
    #pragma unroll
    for(int dy=0;dy<3;dy++)
      #pragma unroll
      for(int dx=0;dx<3;dx++){
        float wv = 0.5f*w1[((c*3+ci)*3+dy)*3+dx];
        if(dy==1 && dx==1) wv += 0.5f*w0[c*3+ci];
        wr[ci][dy][dx] = wv;
      }
  float br = 0.5f*(b0[c] + b1[c]);
  __syncthreads();

  for(int q=qg; q<90; q+=8){
    int yy = q/9, x0 = (q%9)*4;
    float win[3][3][6];
    #pragma unroll
    for(int ci=0;ci<3;ci++)
      #pragma unroll
      for(int dy=0;dy<3;dy++){
        float4 r4 = *(const float4*)&as[ci][yy+dy][x0];
        float2 r2 = *(const float2*)&as[ci][yy+dy][x0+4];
        win[ci][dy][0]=r4.x; win[ci][dy][1]=r4.y; win[ci][dy][2]=r4.z;
        win[ci][dy][3]=r4.w; win[ci][dy][4]=r2.x; win[ci][dy][5]=r2.y;
      }
    #pragma unroll
    for(int p=0;p<4;p++){
      int xx = x0 + p;
      if(xx >= HX) continue;
      int gl = l0 + yy - 1, gn = n0 + xx - 1;
      float val = 0.f;
      if(gl >= 0 && gl < LL && gn >= 0 && gn < NN){
        float s = br;
        #pragma unroll
        for(int ci=0;ci<3;ci++)
          #pragma unroll
          for(int dy=0;dy<3;dy++)
            #pragma unroll
            for(int dx=0;dx<3;dx++)
              s = fmaf(wr[ci][dy][dx], win[ci][dy][p+dx], s);
        val = s*0.5f*(1.f + erff(s*0.70710678118654752f));
      }
      h1s[yy][xx][c] = val;
    }
  }
  __syncthreads();

  int oy = tid >> 5, ox = tid & 31;
  float acc = 0.f;
  #pragma unroll
  for(int dy=0;dy<3;dy++)
    #pragma unroll
    for(int dx=0;dx<3;dx++){
      const float* hh = &h1s[oy+dy][ox+dx][0];
      const float* wt = vwsT + (dy*3+dx)*DMC;
      #pragma unroll
      for(int cg=0;cg<8;cg++){
        float2 h01 = *(const float2*)&hh[cg*4];
        float2 h23 = *(const float2*)&hh[cg*4+2];
        float4 wv = *(const float4*)&wt[cg*4];
        acc = fmaf(h01.x, wv.x, acc);
        acc = fmaf(h01.y, wv.y, acc);
        acc = fmaf(h23.x, wv.z, acc);
        acc = fmaf(h23.y, wv.w, acc);
      }
    }
  float resid = as[0][oy+2][ox+2];
  cot[((size_t)b*LL + l0 + oy)*NN + n0 + ox] = acc + vb0[0] + vb1[0] + resid;
}

// ---------------- K15: tiled GEMM2 (A from co_t, coalesced) + de-normalize ----------------
__global__ __launch_bounds__(256) void k_gemm2(const float* __restrict__ cot, const float* __restrict__ ldw,
    const float* __restrict__ ldb, const float* __restrict__ mean, const float* __restrict__ stdev,
    float* __restrict__ out){
  __shared__ alignas(16) float As[16][68];
  __shared__ alignas(16) float Bs[16][68];
  int tid = threadIdx.x;
  int row0 = blockIdx.x*64, p0 = blockIdx.y*64;
  int b = row0 >> 7, n0 = row0 & 127;
  float acc[4][4] = {};
  int ar = tid & 63, ak = tid >> 6;
  int lk = tid & 15, lr = tid >> 4;
  int tr = tid & 15, tc = tid >> 4;
  for(int k0=0;k0<LL;k0+=16){
    #pragma unroll
    for(int q=0;q<4;q++){
      int k = ak*4 + q;
      As[k][ar] = cot[((size_t)b*LL + k0 + k)*NN + n0 + ar];
    }
    #pragma unroll
    for(int q=0;q<4;q++){
      int cc = lr + 16*q;
      Bs[lk][cc] = ldw[(size_t)(p0+cc)*LL + k0 + lk];
    }
    __syncthreads();
    #pragma unroll
    for(int kk=0;kk<16;kk++){
      float4 av = *(const float4*)&As[kk][4*tr];
      float4 bv = *(const float4*)&Bs[kk][4*tc];
      float aa[4] = {av.x, av.y, av.z, av.w};
      float bb[4] = {bv.x, bv.y, bv.z, bv.w};
      #pragma unroll
      for(int i=0;i<4;i++)
        #pragma unroll
        for(int j=0;j<4;j++) acc[i][j] = fmaf(aa[i], bb[j], acc[i][j]);
    }
    __syncthreads();
  }
  #pragma unroll
  for(int i=0;i<4;i++){
    int row = row0 + 4*tr + i;
    int bb2 = row >> 7, n = row & 127;
    float sd = stdev[row], mu = mean[row];
    #pragma unroll
    for(int j=0;j<4;j++){
      int p = p0 + 4*tc + j;
      float v = (acc[i][j] + ldb[p])*sd + mu;
      out[((size_t)bb2*PREDN + p)*NN + n] = v;
    }
  }
}

extern "C" void kernel_launch(void* const* d_in, const int* in_sizes, int n_in,
                              void* d_out, int out_size, void* d_ws, size_t ws_size,
                              hipStream_t stream){
  (void)in_sizes; (void)n_in; (void)out_size; (void)ws_size;
  const float* batch_x = (const float*)d_in[0];
  const float* le_w  = (const float*)d_in[4];
  const float* le_b  = (const float*)d_in[5];
  const float* c1_w  = (const float*)d_in[6];
  const float* c1_b  = (const float*)d_in[7];
  const float* bn1_g = (const float*)d_in[8];
  const float* bn1_b = (const float*)d_in[9];
  const float* c2_w  = (const float*)d_in[10];
  const float* c2_b  = (const float*)d_in[11];
  const float* bn2_g = (const float*)d_in[12];
  const float* bn2_b = (const float*)d_in[13];
  const float* i1_w0 = (const float*)d_in[14];
  const float* i1_b0 = (const float*)d_in[15];
  const float* i1_w1 = (const float*)d_in[16];
  const float* i1_b1 = (const float*)d_in[17];
  const float* i2_w0 = (const float*)d_in[18];
  const float* i2_b0 = (const float*)d_in[19];
  const float* i2_w1 = (const float*)d_in[20];
  const float* i2_b1 = (const float*)d_in[21];
  const float* ld_w  = (const float*)d_in[22];
  const float* ld_b  = (const float*)d_in[23];
  float* out = (float*)d_out;

  float* ws   = (float*)d_ws;
  float* mean = ws;                      // 2048
  float* stdev= mean + 2048;             // 2048
  float* rstd = stdev + 2048;            // 2048
  float* vwsT = rstd + 2048;             // 288 (+pad 32)
  float* x    = vwsT + 320;              // 16*128*768
  float* a    = x + (size_t)BB*NN*LL;    // 16*3*768*128
  float* t1   = a + (size_t)BB*3*LL*NN;  // 131,072
  float* t1t  = t1 + (size_t)BB*NN*64;   // 131,072
  float* sc1  = t1t + (size_t)BB*64*NN;  // 128
  float* sh1  = sc1 + NN;                // 128
  float* Msp1 = sh1 + NN;                // 131,072
  float* t2   = Msp1 + (size_t)BB*64*NN; // 32,768
  float* t2t  = t2 + (size_t)BB*NN*16;   // 32,768
  float* sc2  = t2t + (size_t)BB*16*NN;  // 128
  float* sh2  = sc2 + NN;                // 128
  float* Msp2 = sh2 + NN;                // 32,768
  float* cot  = Msp2 + (size_t)BB*16*NN; // 16*768*128
  float* a0   = a;                       // channel 0 of a

  k_stats<<<BB, NN, 0, stream>>>(batch_x, mean, stdev, rstd);
  k_prepw<<<1, 256, 0, stream>>>(i2_w0, i2_w1, vwsT);
  k_gemm1<<<dim3(32,12), 256, 0, stream>>>(batch_x, le_w, le_b, mean, rstd, x, a0);
  k_conv1<<<dim3(64,BB), NN, 0, stream>>>(x, c1_w, c1_b, t1);
  k_bnstats<<<NN, 256, 0, stream>>>(t1, bn1_g, bn1_b, BB, 64, sc1, sh1);
  k_bnelu_t<<<dim3(64,BB), NN, 0, stream>>>(t1, sc1, sh1, 64, t1t);
  k_spline_solve<64><<<BB, NN, 0, stream>>>(t1t, Msp1);
  k_spline_eval<64><<<dim3(LL,BB), NN, 0, stream>>>(t1t, Msp1, a, 1);
  k_conv2<<<dim3(16,BB), NN, 0, stream>>>(t1t, c2_w, c2_b, t2);
  k_bnstats<<<NN, 256, 0, stream>>>(t2, bn2_g, bn2_b, BB, 16, sc2, sh2);
  k_bnelu_t<<<dim3(16,BB), NN, 0, stream>>>(t2, sc2, sh2, 16, t2t);
  k_spline_solve<16><<<BB, NN, 0, stream>>>(t2t, Msp2);
  k_spline_eval<16><<<dim3(LL,BB), NN, 0, stream>>>(t2t, Msp2, a, 2);
  k_fusedconv<<<dim3(LL/8, NN/32, BB), 256, 0, stream>>>(a, i1_w0, i1_b0, i1_w1, i1_b1,
                                                         vwsT, i2_b0, i2_b1, cot);
  k_gemm2<<<dim3(32,4), 256, 0, stream>>>(cot, ld_w, ld_b, mean, stdev, out);
}